// Round 1
// baseline (535.940 us; speedup 1.0000x reference)
//
#include <hip/hip_runtime.h>
#include <math.h>

#define NT 256
#define KSEL 20

static __device__ __forceinline__ unsigned long long umin64(unsigned long long a, unsigned long long b) {
    return a < b ? a : b;
}

__global__ __launch_bounds__(NT) void knn_feat_kernel(
    const float* __restrict__ emb0, const float* __restrict__ emb1,
    const float* __restrict__ rctx0, const float* __restrict__ rctx1,
    const int* __restrict__ idx0, const int* __restrict__ idx1,
    float* __restrict__ feats, int N)
{
    const int b = blockIdx.x;
    const int s = blockIdx.y;
    const float* __restrict__ emb  = s ? emb1  : emb0;
    const float* __restrict__ rctx = s ? rctx1 : rctx0;
    const int self = (s ? idx1 : idx0)[b];
    const int tid = threadIdx.x;

    // query vector (E=16), broadcast load, cached
    const float4* arow = (const float4*)(emb + (size_t)self * 16);
    const float4 a0 = arow[0], a1 = arow[1], a2 = arow[2], a3 = arow[3];

    // per-thread sorted (ascending) top-KSEL list of packed keys
    unsigned long long lst[KSEL];
#pragma unroll
    for (int i = 0; i < KSEL; ++i) lst[i] = 0xFFFFFFFFFFFFFFFFULL;

    for (int j = tid; j < N; j += NT) {
        if (j == self) continue;
        const float4* row = (const float4*)(emb + (size_t)j * 16);
        float4 r0 = row[0], r1 = row[1], r2 = row[2], r3 = row[3];
        float t, d2 = 0.f;
        t = r0.x - a0.x; d2 = fmaf(t, t, d2);
        t = r0.y - a0.y; d2 = fmaf(t, t, d2);
        t = r0.z - a0.z; d2 = fmaf(t, t, d2);
        t = r0.w - a0.w; d2 = fmaf(t, t, d2);
        t = r1.x - a1.x; d2 = fmaf(t, t, d2);
        t = r1.y - a1.y; d2 = fmaf(t, t, d2);
        t = r1.z - a1.z; d2 = fmaf(t, t, d2);
        t = r1.w - a1.w; d2 = fmaf(t, t, d2);
        t = r2.x - a2.x; d2 = fmaf(t, t, d2);
        t = r2.y - a2.y; d2 = fmaf(t, t, d2);
        t = r2.z - a2.z; d2 = fmaf(t, t, d2);
        t = r2.w - a2.w; d2 = fmaf(t, t, d2);
        t = r3.x - a3.x; d2 = fmaf(t, t, d2);
        t = r3.y - a3.y; d2 = fmaf(t, t, d2);
        t = r3.z - a3.z; d2 = fmaf(t, t, d2);
        t = r3.w - a3.w; d2 = fmaf(t, t, d2);
        // d2 >= 0 -> float bits monotone; low 32 = index -> JAX tie-break (lower idx wins)
        unsigned long long key = ((unsigned long long)__float_as_uint(d2) << 32) | (unsigned int)j;
        if (key < lst[KSEL - 1]) {
            lst[KSEL - 1] = key;
#pragma unroll
            for (int i = KSEL - 1; i > 0; --i) {
                unsigned long long x = lst[i - 1], y = lst[i];
                bool sw = y < x;
                lst[i - 1] = sw ? y : x;
                lst[i]     = sw ? x : y;
            }
        }
    }

    // dump per-thread lists to LDS for tournament merge
    __shared__ unsigned long long pool[NT * KSEL];
    __shared__ unsigned long long wred[4];
    __shared__ unsigned long long win[KSEL];
#pragma unroll
    for (int i = 0; i < KSEL; ++i) pool[tid * KSEL + i] = lst[i];
    __syncthreads();

    const int lane = tid & 63;
    const int wv = tid >> 6;
    int head = 0;
    for (int r = 0; r < KSEL; ++r) {
        unsigned long long cand = (head < KSEL) ? pool[tid * KSEL + head] : 0xFFFFFFFFFFFFFFFFULL;
        unsigned long long m = cand;
#pragma unroll
        for (int o = 32; o > 0; o >>= 1)
            m = umin64(m, __shfl_xor(m, o, 64));
        if (lane == 0) wred[wv] = m;
        __syncthreads();
        unsigned long long g = umin64(umin64(wred[0], wred[1]), umin64(wred[2], wred[3]));
        if (cand == g) head++;          // keys are unique (index in low bits)
        if (tid == 0) win[r] = g;
        __syncthreads();
    }

    // parallel gather + reduction on wave 0
    if (tid < 64) {
        float w = 0.f, sv = 0.f;
        if (tid < KSEL) {
            unsigned long long g = win[tid];
            float d2 = __uint_as_float((unsigned int)(g >> 32));
            int j = (int)(unsigned int)(g & 0xFFFFFFFFULL);
            float sim = sqrtf(d2) + 0.001f;
            w = expf(-sim);
            sv = rctx[(size_t)b * N + j];
        }
        float sumw = w, sumsw = sv * w, sums = sv, sums2 = sv * sv;
#pragma unroll
        for (int o = 32; o > 0; o >>= 1) {
            sumw  += __shfl_down(sumw,  o, 64);
            sumsw += __shfl_down(sumsw, o, 64);
            sums  += __shfl_down(sums,  o, 64);
            sums2 += __shfl_down(sums2, o, 64);
        }
        if (tid == 0) {
            float f1 = sumw;
            float f2 = sumsw / sumw;
            float mean = sums * (1.f / KSEL);
            float var = (sums2 - (float)KSEL * mean * mean) * (1.f / (KSEL - 1));
            float f3 = sqrtf(fmaxf(var, 0.f));
            feats[b * 8 + 0 + s] = f1;
            feats[b * 8 + 2 + s] = f2;
            feats[b * 8 + 4 + s] = f3;
        }
    }
}

__global__ __launch_bounds__(NT) void mlp_kernel(
    const float* __restrict__ feats,
    const float* __restrict__ mean_in, const float* __restrict__ std_in,
    const float* __restrict__ W1, const float* __restrict__ b1,
    const float* __restrict__ Wm, const float* __restrict__ bm,
    const float* __restrict__ Ws, const float* __restrict__ bs,
    float* __restrict__ out, int B)
{
    __shared__ float sW1[8 * 64];
    __shared__ float sb1[64], sWm[64], sWs[64];
    for (int i = threadIdx.x; i < 512; i += NT) sW1[i] = W1[i];
    if (threadIdx.x < 64) {
        sb1[threadIdx.x] = b1[threadIdx.x];
        sWm[threadIdx.x] = Wm[threadIdx.x];
        sWs[threadIdx.x] = Ws[threadIdx.x];
    }
    __syncthreads();

    int bi = blockIdx.x * blockDim.x + threadIdx.x;
    if (bi < B) {
        float f[8];
#pragma unroll
        for (int i = 0; i < 6; ++i) f[i] = feats[bi * 8 + i];
        f[6] = mean_in[bi];
        f[7] = std_in[bi];
        float mo = 0.f, so = 0.f;
#pragma unroll 4
        for (int j = 0; j < 64; ++j) {
            float h = sb1[j];
#pragma unroll
            for (int i = 0; i < 8; ++i) h = fmaf(f[i], sW1[i * 64 + j], h);
            h = fmaxf(h, 0.f);
            mo = fmaf(h, sWm[j], mo);
            so = fmaf(h, sWs[j], so);
        }
        out[bi]     = mo + bm[0];
        out[B + bi] = so + bs[0];
    }
}

extern "C" void kernel_launch(void* const* d_in, const int* in_sizes, int n_in,
                              void* d_out, int out_size, void* d_ws, size_t ws_size,
                              hipStream_t stream) {
    const float* emb0    = (const float*)d_in[0];
    const float* emb1    = (const float*)d_in[1];
    const float* rctx0   = (const float*)d_in[2];
    const float* rctx1   = (const float*)d_in[3];
    const int*   idx0    = (const int*)d_in[4];
    const int*   idx1    = (const int*)d_in[5];
    const float* mean_in = (const float*)d_in[6];
    const float* std_in  = (const float*)d_in[7];
    const float* W1      = (const float*)d_in[8];
    const float* b1      = (const float*)d_in[9];
    const float* Wm      = (const float*)d_in[10];
    const float* bm      = (const float*)d_in[11];
    const float* Ws      = (const float*)d_in[12];
    const float* bs      = (const float*)d_in[13];

    const int B = in_sizes[4];            // 512
    const int N = in_sizes[0] / 16;       // 50000 (E=16)

    float* feats = (float*)d_ws;          // (B, 8) fp32 = 16 KB

    dim3 g1(B, 2);
    knn_feat_kernel<<<g1, NT, 0, stream>>>(emb0, emb1, rctx0, rctx1, idx0, idx1, feats, N);

    dim3 g2((B + NT - 1) / NT);
    mlp_kernel<<<g2, NT, 0, stream>>>(feats, mean_in, std_in, W1, b1, Wm, bm, Ws, bs,
                                      (float*)d_out, B);
}

// Round 2
// 335.637 us; speedup vs baseline: 1.5968x; 1.5968x over previous
//
#include <hip/hip_runtime.h>
#include <math.h>

typedef unsigned long long u64;
#define INF64 0xFFFFFFFFFFFFFFFFULL
#define NTA 256
#define KSEL 20
#define PREF 16
#define CAP 256

static __device__ __forceinline__ u64 umin64(u64 a, u64 b) { return a < b ? a : b; }

static __device__ __forceinline__ u64 wavemin64(u64 x) {
#pragma unroll
    for (int o = 32; o; o >>= 1) x = umin64(x, __shfl_xor(x, o, 64));
    return x;
}

#define LOAD16(dst, ptr) { const float4* _r = (const float4*)(ptr);            \
    float4 _v0 = _r[0], _v1 = _r[1], _v2 = _r[2], _v3 = _r[3];                 \
    dst[0]=_v0.x; dst[1]=_v0.y; dst[2]=_v0.z; dst[3]=_v0.w;                    \
    dst[4]=_v1.x; dst[5]=_v1.y; dst[6]=_v1.z; dst[7]=_v1.w;                    \
    dst[8]=_v2.x; dst[9]=_v2.y; dst[10]=_v2.z; dst[11]=_v2.w;                  \
    dst[12]=_v3.x; dst[13]=_v3.y; dst[14]=_v3.z; dst[15]=_v3.w; }

// compute the two packed keys for candidate j vs queries A0,A1
static __device__ __forceinline__ void cand_keys(
    const float* __restrict__ emb, int j,
    const float* A0, const float* A1, float na0, float na1,
    u64& key0, u64& key1)
{
    float E[16];
    LOAD16(E, emb + (size_t)j * 16);
    float ne = 0.f, d0 = 0.f, d1 = 0.f;
#pragma unroll
    for (int i = 0; i < 16; ++i) {
        ne = fmaf(E[i], E[i], ne);
        d0 = fmaf(A0[i], E[i], d0);
        d1 = fmaf(A1[i], E[i], d1);
    }
    float dd0 = fmaxf(fmaf(d0, -2.f, na0 + ne), 0.f);
    float dd1 = fmaxf(fmaf(d1, -2.f, na1 + ne), 0.f);
    key0 = ((u64)__float_as_uint(dd0) << 32) | (unsigned int)j;
    key1 = ((u64)__float_as_uint(dd1) << 32) | (unsigned int)j;
}

// Kernel A: per (side, query-pair, N-chunk): filter-scan + exact chunk top-20.
__global__ __launch_bounds__(NTA) void knn_scan_kernel(
    const float* __restrict__ emb0, const float* __restrict__ emb1,
    const int* __restrict__ idx0, const int* __restrict__ idx1,
    u64* __restrict__ chunkTop, int N, int B)
{
    const int tid = threadIdx.x;
    const int bx = blockIdx.x;
    // XCD-aware swizzle (RR heuristic): even XCDs -> side 0, odd -> side 1,
    // so each XCD's 4 MiB L2 holds only one 3.2 MB emb array.
    const int xcd = bx & 7;
    const int s = xcd & 1;
    const int t = (bx >> 3) * 4 + (xcd >> 1);   // [0, 512)
    const int c = t & 1;                        // N-chunk
    const int p = t >> 1;                       // query pair [0, 256)
    const int q0 = 2 * p, q1 = 2 * p + 1;

    const float* __restrict__ emb = s ? emb1 : emb0;
    const int* __restrict__ idxp = s ? idx1 : idx0;
    const int self0 = idxp[q0], self1 = idxp[q1];
    const int half = N >> 1;
    const int jbeg = c * half;
    const int jend = c ? N : half;

    float A0[16], A1[16];
    LOAD16(A0, emb + (size_t)self0 * 16);
    LOAD16(A1, emb + (size_t)self1 * 16);
    float na0 = 0.f, na1 = 0.f;
#pragma unroll
    for (int i = 0; i < 16; ++i) {
        na0 = fmaf(A0[i], A0[i], na0);
        na1 = fmaf(A1[i], A1[i], na1);
    }

    __shared__ u64 smin[2][NTA];
    __shared__ u64 sbuf[2][CAP];
    __shared__ int scnt[2];
    __shared__ u64 sbound[2];

    // ---- prefix: per-thread min over first PREF*NTA candidates of the chunk
    u64 mn0 = INF64, mn1 = INF64;
    for (int k = 0; k < PREF; ++k) {
        int j = jbeg + (k << 8) + tid;
        u64 k0, k1;
        cand_keys(emb, j, A0, A1, na0, na1, k0, k1);
        mn0 = umin64(mn0, k0);
        mn1 = umin64(mn1, k1);
    }
    smin[0][tid] = mn0;
    smin[1][tid] = mn1;
    if (tid == 0) { scnt[0] = 0; scnt[1] = 0; }
    __syncthreads();

    // ---- wave 0: 21st-smallest of 256 thread-mins = guaranteed bound
    if (tid < 64) {
        u64 v0[4], v1[4];
#pragma unroll
        for (int k = 0; k < 4; ++k) {
            v0[k] = smin[0][tid + 64 * k];
            v1[k] = smin[1][tid + 64 * k];
        }
        u64 g0 = 0, g1 = 0;
        for (int r = 0; r < 21; ++r) {
            u64 c0 = umin64(umin64(v0[0], v0[1]), umin64(v0[2], v0[3]));
            u64 c1 = umin64(umin64(v1[0], v1[1]), umin64(v1[2], v1[3]));
            g0 = wavemin64(c0);
            g1 = wavemin64(c1);
#pragma unroll
            for (int k = 0; k < 4; ++k) {
                if (v0[k] == g0) v0[k] = INF64;
                if (v1[k] == g1) v1[k] = INF64;
            }
        }
        if (tid == 0) {
            // +2 ulp (in d2 bits) slack + all-index mask: immunity to fp
            // contraction differences between prefix and main loop.
            sbound[0] = (g0 | 0xFFFFFFFFULL) + (2ULL << 32);
            sbound[1] = (g1 | 0xFFFFFFFFULL) + (2ULL << 32);
        }
    }
    __syncthreads();
    const u64 bound0 = sbound[0], bound1 = sbound[1];

    // ---- main filtered scan
    for (int j = jbeg + tid; j < jend; j += NTA) {
        u64 k0, k1;
        cand_keys(emb, j, A0, A1, na0, na1, k0, k1);
        if (k0 <= bound0 && j != self0) {
            int sl = atomicAdd(&scnt[0], 1);
            if (sl < CAP) sbuf[0][sl] = k0;
        }
        if (k1 <= bound1 && j != self1) {
            int sl = atomicAdd(&scnt[1], 1);
            if (sl < CAP) sbuf[1][sl] = k1;
        }
    }
    __syncthreads();

    // ---- wave 0: exact top-20 of survivors, write to ws
    if (tid < 64) {
        const int M0 = min(scnt[0], CAP);
        const int M1 = min(scnt[1], CAP);
        u64 v0[4], v1[4];
#pragma unroll
        for (int k = 0; k < 4; ++k) {
            int i = tid + 64 * k;
            v0[k] = (i < M0) ? sbuf[0][i] : INF64;
            v1[k] = (i < M1) ? sbuf[1][i] : INF64;
        }
        u64 keep0 = INF64, keep1 = INF64;
        for (int r = 0; r < KSEL; ++r) {
            u64 c0 = umin64(umin64(v0[0], v0[1]), umin64(v0[2], v0[3]));
            u64 c1 = umin64(umin64(v1[0], v1[1]), umin64(v1[2], v1[3]));
            u64 g0 = wavemin64(c0);
            u64 g1 = wavemin64(c1);
#pragma unroll
            for (int k = 0; k < 4; ++k) {
                if (v0[k] == g0) v0[k] = INF64;
                if (v1[k] == g1) v1[k] = INF64;
            }
            if (tid == r) { keep0 = g0; keep1 = g1; }
        }
        if (tid < KSEL) {
            u64* dst0 = chunkTop + (((size_t)(s * B + q0) * 2 + c) * KSEL);
            u64* dst1 = chunkTop + (((size_t)(s * B + q1) * 2 + c) * KSEL);
            dst0[tid] = keep0;
            dst1[tid] = keep1;
        }
    }
}

// Kernel B: per row b: merge 2 chunk-top-20s per side -> global top-20,
// gather rctx, compute f1/f2/f3, then the fused MLP row.
__global__ __launch_bounds__(64) void merge_mlp_kernel(
    const u64* __restrict__ chunkTop,
    const float* __restrict__ rctx0, const float* __restrict__ rctx1,
    const float* __restrict__ mean_in, const float* __restrict__ std_in,
    const float* __restrict__ W1, const float* __restrict__ b1,
    const float* __restrict__ Wm, const float* __restrict__ bm,
    const float* __restrict__ Ws, const float* __restrict__ bs,
    float* __restrict__ out, int N, int B)
{
    const int b = blockIdx.x;
    const int lane = threadIdx.x;
    __shared__ float sf[8];

#pragma unroll
    for (int s = 0; s < 2; ++s) {
        const u64* src = chunkTop + ((size_t)(s * B + b) * 2) * KSEL; // 40 keys
        u64 key = (lane < 2 * KSEL) ? src[lane] : INF64;
        u64 keep = INF64;
        for (int r = 0; r < KSEL; ++r) {
            u64 g = wavemin64(key);
            if (key == g) key = INF64;
            if (lane == r) keep = g;
        }
        float w = 0.f, sv = 0.f;
        if (lane < KSEL) {
            float d2 = __uint_as_float((unsigned int)(keep >> 32));
            int j = (int)(unsigned int)(keep & 0xFFFFFFFFULL);
            float sim = sqrtf(d2) + 0.001f;
            w = expf(-sim);
            const float* __restrict__ rctx = s ? rctx1 : rctx0;
            sv = rctx[(size_t)b * N + j];
        }
        float sw = w, ssw = sv * w, ss = sv, ss2 = sv * sv;
#pragma unroll
        for (int o = 32; o; o >>= 1) {
            sw  += __shfl_down(sw,  o, 64);
            ssw += __shfl_down(ssw, o, 64);
            ss  += __shfl_down(ss,  o, 64);
            ss2 += __shfl_down(ss2, o, 64);
        }
        if (lane == 0) {
            sf[0 + s] = sw;
            sf[2 + s] = ssw / sw;
            float mean = ss * (1.f / KSEL);
            float var = (ss2 - (float)KSEL * mean * mean) * (1.f / (KSEL - 1));
            sf[4 + s] = sqrtf(fmaxf(var, 0.f));
        }
    }
    if (lane == 0) { sf[6] = mean_in[b]; sf[7] = std_in[b]; }
    __syncthreads();

    float f[8];
#pragma unroll
    for (int i = 0; i < 8; ++i) f[i] = sf[i];
    float h = b1[lane];
#pragma unroll
    for (int i = 0; i < 8; ++i) h = fmaf(f[i], W1[i * 64 + lane], h);
    h = fmaxf(h, 0.f);
    float mo = h * Wm[lane], so = h * Ws[lane];
#pragma unroll
    for (int o = 32; o; o >>= 1) {
        mo += __shfl_down(mo, o, 64);
        so += __shfl_down(so, o, 64);
    }
    if (lane == 0) {
        out[b] = mo + bm[0];
        out[B + b] = so + bs[0];
    }
}

extern "C" void kernel_launch(void* const* d_in, const int* in_sizes, int n_in,
                              void* d_out, int out_size, void* d_ws, size_t ws_size,
                              hipStream_t stream) {
    const float* emb0    = (const float*)d_in[0];
    const float* emb1    = (const float*)d_in[1];
    const float* rctx0   = (const float*)d_in[2];
    const float* rctx1   = (const float*)d_in[3];
    const int*   idx0    = (const int*)d_in[4];
    const int*   idx1    = (const int*)d_in[5];
    const float* mean_in = (const float*)d_in[6];
    const float* std_in  = (const float*)d_in[7];
    const float* W1      = (const float*)d_in[8];
    const float* b1      = (const float*)d_in[9];
    const float* Wm      = (const float*)d_in[10];
    const float* bm      = (const float*)d_in[11];
    const float* Ws      = (const float*)d_in[12];
    const float* bs      = (const float*)d_in[13];

    const int B = in_sizes[4];          // 512
    const int N = in_sizes[0] / 16;     // 50000

    u64* chunkTop = (u64*)d_ws;         // [2][B][2][20] u64 = 320 KB

    // 2 sides x (B/2) query-pairs x 2 N-chunks = 1024 blocks
    knn_scan_kernel<<<dim3(2 * (B / 2) * 2), NTA, 0, stream>>>(
        emb0, emb1, idx0, idx1, chunkTop, N, B);

    merge_mlp_kernel<<<dim3(B), 64, 0, stream>>>(
        chunkTop, rctx0, rctx1, mean_in, std_in,
        W1, b1, Wm, bm, Ws, bs, (float*)d_out, N, B);
}

// Round 3
// 303.077 us; speedup vs baseline: 1.7683x; 1.1074x over previous
//
#include <hip/hip_runtime.h>
#include <math.h>

typedef unsigned long long u64;
#define INF64 0xFFFFFFFFFFFFFFFFULL
#define NTA 256
#define KSEL 20
#define QB 4      // queries per block
#define CNK 8     // N-chunks
#define PREF 4    // prefix sample iterations (PREF*256 rows)
#define CAP 384   // survivor buffer per query

static __device__ __forceinline__ u64 umin64(u64 a, u64 b) { return a < b ? a : b; }

static __device__ __forceinline__ u64 wavemin64(u64 x) {
#pragma unroll
    for (int o = 32; o; o >>= 1) x = umin64(x, __shfl_xor(x, o, 64));
    return x;
}

#define LOAD16(dst, ptr) { const float4* _r = (const float4*)(ptr);            \
    float4 _v0 = _r[0], _v1 = _r[1], _v2 = _r[2], _v3 = _r[3];                 \
    dst[0]=_v0.x; dst[1]=_v0.y; dst[2]=_v0.z; dst[3]=_v0.w;                    \
    dst[4]=_v1.x; dst[5]=_v1.y; dst[6]=_v1.z; dst[7]=_v1.w;                    \
    dst[8]=_v2.x; dst[9]=_v2.y; dst[10]=_v2.z; dst[11]=_v2.w;                  \
    dst[12]=_v3.x; dst[13]=_v3.y; dst[14]=_v3.z; dst[15]=_v3.w; }

// keys for candidate j vs QB queries; identical instruction sequence in
// prefix and main scan -> bit-identical keys (bound logic relies on this)
static __device__ __forceinline__ void keys4(
    const float* __restrict__ emb, int j,
    const float* A, const float* na, u64* kk)
{
    float E[16];
    LOAD16(E, emb + (size_t)j * 16);
    float ne = 0.f;
#pragma unroll
    for (int i = 0; i < 16; ++i) ne = fmaf(E[i], E[i], ne);
#pragma unroll
    for (int q = 0; q < QB; ++q) {
        float d = 0.f;
#pragma unroll
        for (int i = 0; i < 16; ++i) d = fmaf(A[q * 16 + i], E[i], d);
        float dd = fmaxf(fmaf(d, -2.f, na[q] + ne), 0.f);
        kk[q] = ((u64)__float_as_uint(dd) << 32) | (unsigned int)j;
    }
}

// Kernel A: per (side, 4-query group, N-chunk): bound from prefix sample,
// filtered scan, exact per-chunk top-20 (wave w owns query w).
__global__ __launch_bounds__(NTA) void knn_scan_kernel(
    const float* __restrict__ emb0, const float* __restrict__ emb1,
    const int* __restrict__ idx0, const int* __restrict__ idx1,
    u64* __restrict__ chunkTop, int N, int B)
{
    const int tid = threadIdx.x;
    const int lane = tid & 63;
    const int wv = tid >> 6;
    const int bx = blockIdx.x;
    // XCD swizzle: even XCDs side 0, odd side 1 -> each XCD L2 holds one emb
    const int xcd = bx & 7;
    const int s = xcd & 1;
    const int t = (bx >> 3) * 4 + (xcd >> 1);   // [0, (B/QB)*CNK)
    const int c = t & (CNK - 1);
    const int g = t >> 3;                        // query group [0, B/QB)

    const float* __restrict__ emb = s ? emb1 : emb0;
    const int* __restrict__ idxp = s ? idx1 : idx0;
    int self[QB];
#pragma unroll
    for (int q = 0; q < QB; ++q) self[q] = idxp[QB * g + q];

    const int chunkLen = (N + CNK - 1) / CNK;
    const int jbeg = c * chunkLen;
    const int jend = min(N, jbeg + chunkLen);

    float A[QB * 16], na[QB];
#pragma unroll
    for (int q = 0; q < QB; ++q) {
        LOAD16((&A[q * 16]), emb + (size_t)self[q] * 16);
        float v = 0.f;
#pragma unroll
        for (int i = 0; i < 16; ++i) v = fmaf(A[q * 16 + i], A[q * 16 + i], v);
        na[q] = v;
    }

    __shared__ u64 smin[QB][NTA];
    __shared__ u64 sbuf[QB][CAP];
    __shared__ int scnt[QB];
    __shared__ u64 sbound[QB];

    // ---- prefix sample: per-thread min over PREF*256 rows
    u64 mn[QB];
#pragma unroll
    for (int q = 0; q < QB; ++q) mn[q] = INF64;
    for (int k = 0; k < PREF; ++k) {
        int j = jbeg + (k << 8) + tid;
        u64 kk[QB];
        keys4(emb, j, A, na, kk);
#pragma unroll
        for (int q = 0; q < QB; ++q) mn[q] = umin64(mn[q], kk[q]);
    }
#pragma unroll
    for (int q = 0; q < QB; ++q) smin[q][tid] = mn[q];
    if (tid < QB) scnt[tid] = 0;
    __syncthreads();

    // ---- wave wv: 21st-smallest of its query's 256 thread-mins = bound
    {
        u64 v[4];
#pragma unroll
        for (int k = 0; k < 4; ++k) v[k] = smin[wv][lane + 64 * k];
        u64 gmin = 0;
        for (int r = 0; r < KSEL + 1; ++r) {
            gmin = wavemin64(umin64(umin64(v[0], v[1]), umin64(v[2], v[3])));
#pragma unroll
            for (int k = 0; k < 4; ++k) if (v[k] == gmin) v[k] = INF64;
        }
        if (lane == 0)
            sbound[wv] = (gmin | 0xFFFFFFFFULL) + (2ULL << 32); // slack + idx mask
    }
    __syncthreads();
    u64 bound[QB];
#pragma unroll
    for (int q = 0; q < QB; ++q) bound[q] = sbound[q];

    // ---- main filtered scan over the chunk
    for (int j = jbeg + tid; j < jend; j += NTA) {
        u64 kk[QB];
        keys4(emb, j, A, na, kk);
#pragma unroll
        for (int q = 0; q < QB; ++q) {
            if (kk[q] <= bound[q] && j != self[q]) {
                int sl = atomicAdd(&scnt[q], 1);
                if (sl < CAP) sbuf[q][sl] = kk[q];
            }
        }
    }
    __syncthreads();

    // ---- wave wv: exact top-20 of its query's survivors
    {
        const int M = min(scnt[wv], CAP);
        u64 v[CAP / 64];
#pragma unroll
        for (int k = 0; k < CAP / 64; ++k) {
            int i = lane + 64 * k;
            v[k] = (i < M) ? sbuf[wv][i] : INF64;
        }
        u64 keep = INF64;
        for (int r = 0; r < KSEL; ++r) {
            u64 cm = v[0];
#pragma unroll
            for (int k = 1; k < CAP / 64; ++k) cm = umin64(cm, v[k]);
            u64 gmin = wavemin64(cm);
#pragma unroll
            for (int k = 0; k < CAP / 64; ++k) if (v[k] == gmin) v[k] = INF64;
            if (lane == r) keep = gmin;
        }
        if (lane < KSEL) {
            int q = QB * g + wv;
            chunkTop[(((size_t)(s * B + q)) * CNK + c) * KSEL + lane] = keep;
        }
    }
}

// Kernel B: per row b: wave s merges its side's CNK chunk-top-20s -> top-20,
// gathers rctx, computes f1/f2/f3; then lanes 0-63 run the fused MLP.
__global__ __launch_bounds__(128) void merge_mlp_kernel(
    const u64* __restrict__ chunkTop,
    const float* __restrict__ rctx0, const float* __restrict__ rctx1,
    const float* __restrict__ mean_in, const float* __restrict__ std_in,
    const float* __restrict__ W1, const float* __restrict__ b1,
    const float* __restrict__ Wm, const float* __restrict__ bm,
    const float* __restrict__ Ws, const float* __restrict__ bs,
    float* __restrict__ out, int N, int B)
{
    const int b = blockIdx.x;
    const int tid = threadIdx.x;
    const int s = tid >> 6;
    const int lane = tid & 63;
    __shared__ float sf[8];

    const u64* src = chunkTop + ((size_t)(s * B + b)) * CNK * KSEL; // 160 keys
    u64 v0 = src[lane];
    u64 v1 = src[lane + 64];
    u64 v2 = (lane < CNK * KSEL - 128) ? src[lane + 128] : INF64;
    u64 keep = INF64;
    for (int r = 0; r < KSEL; ++r) {
        u64 gmin = wavemin64(umin64(v0, umin64(v1, v2)));
        if (v0 == gmin) v0 = INF64;
        if (v1 == gmin) v1 = INF64;
        if (v2 == gmin) v2 = INF64;
        if (lane == r) keep = gmin;
    }
    float w = 0.f, sv = 0.f;
    if (lane < KSEL) {
        float d2 = __uint_as_float((unsigned int)(keep >> 32));
        int j = (int)(unsigned int)(keep & 0xFFFFFFFFULL);
        float sim = sqrtf(d2) + 0.001f;
        w = expf(-sim);
        const float* __restrict__ rctx = s ? rctx1 : rctx0;
        sv = rctx[(size_t)b * N + j];
    }
    float sw = w, ssw = sv * w, ss = sv, ss2 = sv * sv;
#pragma unroll
    for (int o = 32; o; o >>= 1) {
        sw  += __shfl_down(sw,  o, 64);
        ssw += __shfl_down(ssw, o, 64);
        ss  += __shfl_down(ss,  o, 64);
        ss2 += __shfl_down(ss2, o, 64);
    }
    if (lane == 0) {
        sf[0 + s] = sw;
        sf[2 + s] = ssw / sw;
        float mean = ss * (1.f / KSEL);
        float var = (ss2 - (float)KSEL * mean * mean) * (1.f / (KSEL - 1));
        sf[4 + s] = sqrtf(fmaxf(var, 0.f));
        if (s == 0) { sf[6] = mean_in[b]; sf[7] = std_in[b]; }
    }
    __syncthreads();

    if (tid < 64) {
        float f[8];
#pragma unroll
        for (int i = 0; i < 8; ++i) f[i] = sf[i];
        float h = b1[lane];
#pragma unroll
        for (int i = 0; i < 8; ++i) h = fmaf(f[i], W1[i * 64 + lane], h);
        h = fmaxf(h, 0.f);
        float mo = h * Wm[lane], so = h * Ws[lane];
#pragma unroll
        for (int o = 32; o; o >>= 1) {
            mo += __shfl_down(mo, o, 64);
            so += __shfl_down(so, o, 64);
        }
        if (lane == 0) {
            out[b] = mo + bm[0];
            out[B + b] = so + bs[0];
        }
    }
}

extern "C" void kernel_launch(void* const* d_in, const int* in_sizes, int n_in,
                              void* d_out, int out_size, void* d_ws, size_t ws_size,
                              hipStream_t stream) {
    const float* emb0    = (const float*)d_in[0];
    const float* emb1    = (const float*)d_in[1];
    const float* rctx0   = (const float*)d_in[2];
    const float* rctx1   = (const float*)d_in[3];
    const int*   idx0    = (const int*)d_in[4];
    const int*   idx1    = (const int*)d_in[5];
    const float* mean_in = (const float*)d_in[6];
    const float* std_in  = (const float*)d_in[7];
    const float* W1      = (const float*)d_in[8];
    const float* b1      = (const float*)d_in[9];
    const float* Wm      = (const float*)d_in[10];
    const float* bm      = (const float*)d_in[11];
    const float* Ws      = (const float*)d_in[12];
    const float* bs      = (const float*)d_in[13];

    const int B = in_sizes[4];          // 512
    const int N = in_sizes[0] / 16;     // 50000

    u64* chunkTop = (u64*)d_ws;         // [2][B][CNK][20] u64 = 1.31 MB

    // 2 sides x (B/QB) query groups x CNK chunks = 2048 blocks
    knn_scan_kernel<<<dim3(2 * (B / QB) * CNK), NTA, 0, stream>>>(
        emb0, emb1, idx0, idx1, chunkTop, N, B);

    merge_mlp_kernel<<<dim3(B), 128, 0, stream>>>(
        chunkTop, rctx0, rctx1, mean_in, std_in,
        W1, b1, Wm, bm, Ws, bs, (float*)d_out, N, B);
}

// Round 4
// 298.196 us; speedup vs baseline: 1.7973x; 1.0164x over previous
//
#include <hip/hip_runtime.h>
#include <math.h>

typedef unsigned long long u64;
#define INF64 0xFFFFFFFFFFFFFFFFULL
#define FBIG 3.3e38f
#define NTA 256
#define KSEL 20
#define QB 4      // queries per block (must equal waves/block)
#define CNK 8     // N-chunks
#define PREF 4    // prefix sample iterations (PREF*256 rows)
#define CAP 384   // survivor buffer per query

static __device__ __forceinline__ u64 umin64(u64 a, u64 b) { return a < b ? a : b; }

static __device__ __forceinline__ float dot16(
    float4 a0, float4 a1, float4 a2, float4 a3,
    float4 b0, float4 b1, float4 b2, float4 b3)
{
    float d = 0.f;
    d = fmaf(a0.x, b0.x, d); d = fmaf(a0.y, b0.y, d);
    d = fmaf(a0.z, b0.z, d); d = fmaf(a0.w, b0.w, d);
    d = fmaf(a1.x, b1.x, d); d = fmaf(a1.y, b1.y, d);
    d = fmaf(a1.z, b1.z, d); d = fmaf(a1.w, b1.w, d);
    d = fmaf(a2.x, b2.x, d); d = fmaf(a2.y, b2.y, d);
    d = fmaf(a2.z, b2.z, d); d = fmaf(a2.w, b2.w, d);
    d = fmaf(a3.x, b3.x, d); d = fmaf(a3.y, b3.y, d);
    d = fmaf(a3.z, b3.z, d); d = fmaf(a3.w, b3.w, d);
    return d;
}

// Kernel A: per (side, 4-query group, N-chunk). Wave w owns query w for the
// selection phases. NO private arrays anywhere: everything in named regs
// (R3's float A[64] was address-taken -> scratch spill -> VGPR_Count=36).
__global__ __launch_bounds__(NTA) void knn_scan_kernel(
    const float* __restrict__ emb0, const float* __restrict__ emb1,
    const int* __restrict__ idx0, const int* __restrict__ idx1,
    u64* __restrict__ chunkTop, int N, int B)
{
    const int tid = threadIdx.x;
    const int lane = tid & 63;
    const int wv = tid >> 6;
    const int bx = blockIdx.x;
    // XCD swizzle: even XCDs side 0, odd side 1 -> each XCD L2 holds one emb
    const int xcd = bx & 7;
    const int s = xcd & 1;
    const int t = (bx >> 3) * 4 + (xcd >> 1);   // [0, (B/QB)*CNK)
    const int c = t & (CNK - 1);
    const int g = t >> 3;                        // query group

    const float* __restrict__ emb = s ? emb1 : emb0;
    const int* __restrict__ idxp = s ? idx1 : idx0;
    const int qbase = QB * g;
    const int self0 = idxp[qbase + 0];
    const int self1 = idxp[qbase + 1];
    const int self2 = idxp[qbase + 2];
    const int self3 = idxp[qbase + 3];

    const int chunkLen = (N + CNK - 1) / CNK;
    const int jbeg = c * chunkLen;
    const int jend = min(N, jbeg + chunkLen);

    float4 q00, q01, q02, q03, q10, q11, q12, q13;
    float4 q20, q21, q22, q23, q30, q31, q32, q33;
    { const float4* p = (const float4*)(emb + (size_t)self0 * 16); q00 = p[0]; q01 = p[1]; q02 = p[2]; q03 = p[3]; }
    { const float4* p = (const float4*)(emb + (size_t)self1 * 16); q10 = p[0]; q11 = p[1]; q12 = p[2]; q13 = p[3]; }
    { const float4* p = (const float4*)(emb + (size_t)self2 * 16); q20 = p[0]; q21 = p[1]; q22 = p[2]; q23 = p[3]; }
    { const float4* p = (const float4*)(emb + (size_t)self3 * 16); q30 = p[0]; q31 = p[1]; q32 = p[2]; q33 = p[3]; }
    const float na0 = dot16(q00, q01, q02, q03, q00, q01, q02, q03);
    const float na1 = dot16(q10, q11, q12, q13, q10, q11, q12, q13);
    const float na2 = dot16(q20, q21, q22, q23, q20, q21, q22, q23);
    const float na3 = dot16(q30, q31, q32, q33, q30, q31, q32, q33);

    __shared__ float sminf[QB][NTA];
    __shared__ u64 sbuf[QB][CAP];
    __shared__ int scnt[QB];
    __shared__ float sboundf[QB];

    // ---- prefix sample: per-thread float-d2 min over PREF*256 rows
    float mn0 = FBIG, mn1 = FBIG, mn2 = FBIG, mn3 = FBIG;
#pragma unroll
    for (int k = 0; k < PREF; ++k) {
        const int j = jbeg + (k << 8) + tid;
        const float4* p = (const float4*)(emb + (size_t)j * 16);
        float4 e0 = p[0], e1 = p[1], e2 = p[2], e3 = p[3];
        const float ne = dot16(e0, e1, e2, e3, e0, e1, e2, e3);
        float dd;
        dd = fmaxf(fmaf(dot16(q00, q01, q02, q03, e0, e1, e2, e3), -2.f, na0 + ne), 0.f); mn0 = fminf(mn0, dd);
        dd = fmaxf(fmaf(dot16(q10, q11, q12, q13, e0, e1, e2, e3), -2.f, na1 + ne), 0.f); mn1 = fminf(mn1, dd);
        dd = fmaxf(fmaf(dot16(q20, q21, q22, q23, e0, e1, e2, e3), -2.f, na2 + ne), 0.f); mn2 = fminf(mn2, dd);
        dd = fmaxf(fmaf(dot16(q30, q31, q32, q33, e0, e1, e2, e3), -2.f, na3 + ne), 0.f); mn3 = fminf(mn3, dd);
    }
    sminf[0][tid] = mn0; sminf[1][tid] = mn1; sminf[2][tid] = mn2; sminf[3][tid] = mn3;
    if (tid < QB) scnt[tid] = 0;
    __syncthreads();

    // ---- wave wv: 21st-smallest of its query's 256 thread-mins = bound.
    // (duplicate values removed together is safe: still >=21 distinct
    // candidates <= bound after 21 rounds)
    {
        float v0 = sminf[wv][lane];
        float v1 = sminf[wv][lane + 64];
        float v2 = sminf[wv][lane + 128];
        float v3 = sminf[wv][lane + 192];
        float gm = 0.f;
        for (int r = 0; r < KSEL + 1; ++r) {
            float cm = fminf(fminf(v0, v1), fminf(v2, v3));
#pragma unroll
            for (int o = 32; o; o >>= 1) cm = fminf(cm, __shfl_xor(cm, o, 64));
            gm = cm;
            if (v0 == gm) v0 = FBIG;
            if (v1 == gm) v1 = FBIG;
            if (v2 == gm) v2 = FBIG;
            if (v3 == gm) v3 = FBIG;
        }
        // +2 ulp slack (fp-contraction immunity); d2>=0 so bits are monotone
        if (lane == 0) sboundf[wv] = __uint_as_float(__float_as_uint(gm) + 2);
    }
    __syncthreads();
    const float bnd0 = sboundf[0], bnd1 = sboundf[1];
    const float bnd2 = sboundf[2], bnd3 = sboundf[3];

    // ---- main filtered scan (float compare; pack key only on survival)
    for (int j = jbeg + tid; j < jend; j += NTA) {
        const float4* p = (const float4*)(emb + (size_t)j * 16);
        float4 e0 = p[0], e1 = p[1], e2 = p[2], e3 = p[3];
        const float ne = dot16(e0, e1, e2, e3, e0, e1, e2, e3);
        const float dd0 = fmaxf(fmaf(dot16(q00, q01, q02, q03, e0, e1, e2, e3), -2.f, na0 + ne), 0.f);
        const float dd1 = fmaxf(fmaf(dot16(q10, q11, q12, q13, e0, e1, e2, e3), -2.f, na1 + ne), 0.f);
        const float dd2 = fmaxf(fmaf(dot16(q20, q21, q22, q23, e0, e1, e2, e3), -2.f, na2 + ne), 0.f);
        const float dd3 = fmaxf(fmaf(dot16(q30, q31, q32, q33, e0, e1, e2, e3), -2.f, na3 + ne), 0.f);
        if (dd0 <= bnd0 && j != self0) {
            int sl = atomicAdd(&scnt[0], 1);
            if (sl < CAP) sbuf[0][sl] = ((u64)__float_as_uint(dd0) << 32) | (unsigned)j;
        }
        if (dd1 <= bnd1 && j != self1) {
            int sl = atomicAdd(&scnt[1], 1);
            if (sl < CAP) sbuf[1][sl] = ((u64)__float_as_uint(dd1) << 32) | (unsigned)j;
        }
        if (dd2 <= bnd2 && j != self2) {
            int sl = atomicAdd(&scnt[2], 1);
            if (sl < CAP) sbuf[2][sl] = ((u64)__float_as_uint(dd2) << 32) | (unsigned)j;
        }
        if (dd3 <= bnd3 && j != self3) {
            int sl = atomicAdd(&scnt[3], 1);
            if (sl < CAP) sbuf[3][sl] = ((u64)__float_as_uint(dd3) << 32) | (unsigned)j;
        }
    }
    __syncthreads();

    // ---- wave wv: exact top-20 of its query's survivors (keys unique)
    {
        const int M = min(scnt[wv], CAP);
        u64 t0 = (lane < M)       ? sbuf[wv][lane]       : INF64;
        u64 t1 = (lane + 64 < M)  ? sbuf[wv][lane + 64]  : INF64;
        u64 t2 = (lane + 128 < M) ? sbuf[wv][lane + 128] : INF64;
        u64 t3 = (lane + 192 < M) ? sbuf[wv][lane + 192] : INF64;
        u64 t4 = (lane + 256 < M) ? sbuf[wv][lane + 256] : INF64;
        u64 t5 = (lane + 320 < M) ? sbuf[wv][lane + 320] : INF64;
        u64 keep = INF64;
        for (int r = 0; r < KSEL; ++r) {
            u64 cm = umin64(umin64(umin64(t0, t1), umin64(t2, t3)), umin64(t4, t5));
#pragma unroll
            for (int o = 32; o; o >>= 1) cm = umin64(cm, __shfl_xor(cm, o, 64));
            if (t0 == cm) t0 = INF64;
            if (t1 == cm) t1 = INF64;
            if (t2 == cm) t2 = INF64;
            if (t3 == cm) t3 = INF64;
            if (t4 == cm) t4 = INF64;
            if (t5 == cm) t5 = INF64;
            if (lane == r) keep = cm;
        }
        if (lane < KSEL)
            chunkTop[(((size_t)(s * B + qbase + wv)) * CNK + c) * KSEL + lane] = keep;
    }
}

// Kernel B: per row b: wave s merges its side's CNK chunk-top-20s -> top-20,
// gathers rctx, computes f1/f2/f3; then lanes 0-63 run the fused MLP.
__global__ __launch_bounds__(128) void merge_mlp_kernel(
    const u64* __restrict__ chunkTop,
    const float* __restrict__ rctx0, const float* __restrict__ rctx1,
    const float* __restrict__ mean_in, const float* __restrict__ std_in,
    const float* __restrict__ W1, const float* __restrict__ b1,
    const float* __restrict__ Wm, const float* __restrict__ bm,
    const float* __restrict__ Ws, const float* __restrict__ bs,
    float* __restrict__ out, int N, int B)
{
    const int b = blockIdx.x;
    const int tid = threadIdx.x;
    const int s = tid >> 6;
    const int lane = tid & 63;
    __shared__ float sf[8];

    const u64* src = chunkTop + ((size_t)(s * B + b)) * CNK * KSEL; // 160 keys
    u64 v0 = src[lane];
    u64 v1 = src[lane + 64];
    u64 v2 = (lane < CNK * KSEL - 128) ? src[lane + 128] : INF64;
    u64 keep = INF64;
    for (int r = 0; r < KSEL; ++r) {
        u64 cm = umin64(v0, umin64(v1, v2));
#pragma unroll
        for (int o = 32; o; o >>= 1) cm = umin64(cm, __shfl_xor(cm, o, 64));
        if (v0 == cm) v0 = INF64;
        if (v1 == cm) v1 = INF64;
        if (v2 == cm) v2 = INF64;
        if (lane == r) keep = cm;
    }
    float w = 0.f, sv = 0.f;
    if (lane < KSEL) {
        float d2 = __uint_as_float((unsigned int)(keep >> 32));
        int j = (int)(unsigned int)(keep & 0xFFFFFFFFULL);
        float sim = sqrtf(d2) + 0.001f;
        w = expf(-sim);
        const float* __restrict__ rctx = s ? rctx1 : rctx0;
        sv = rctx[(size_t)b * N + j];
    }
    float sw = w, ssw = sv * w, ss = sv, ss2 = sv * sv;
#pragma unroll
    for (int o = 32; o; o >>= 1) {
        sw  += __shfl_down(sw,  o, 64);
        ssw += __shfl_down(ssw, o, 64);
        ss  += __shfl_down(ss,  o, 64);
        ss2 += __shfl_down(ss2, o, 64);
    }
    if (lane == 0) {
        sf[0 + s] = sw;
        sf[2 + s] = ssw / sw;
        float mean = ss * (1.f / KSEL);
        float var = (ss2 - (float)KSEL * mean * mean) * (1.f / (KSEL - 1));
        sf[4 + s] = sqrtf(fmaxf(var, 0.f));
        if (s == 0) { sf[6] = mean_in[b]; sf[7] = std_in[b]; }
    }
    __syncthreads();

    if (tid < 64) {
        float f0 = sf[0], f1 = sf[1], f2 = sf[2], f3 = sf[3];
        float f4 = sf[4], f5 = sf[5], f6 = sf[6], f7 = sf[7];
        float h = b1[lane];
        h = fmaf(f0, W1[0 * 64 + lane], h);
        h = fmaf(f1, W1[1 * 64 + lane], h);
        h = fmaf(f2, W1[2 * 64 + lane], h);
        h = fmaf(f3, W1[3 * 64 + lane], h);
        h = fmaf(f4, W1[4 * 64 + lane], h);
        h = fmaf(f5, W1[5 * 64 + lane], h);
        h = fmaf(f6, W1[6 * 64 + lane], h);
        h = fmaf(f7, W1[7 * 64 + lane], h);
        h = fmaxf(h, 0.f);
        float mo = h * Wm[lane], so = h * Ws[lane];
#pragma unroll
        for (int o = 32; o; o >>= 1) {
            mo += __shfl_down(mo, o, 64);
            so += __shfl_down(so, o, 64);
        }
        if (lane == 0) {
            out[b] = mo + bm[0];
            out[B + b] = so + bs[0];
        }
    }
}

extern "C" void kernel_launch(void* const* d_in, const int* in_sizes, int n_in,
                              void* d_out, int out_size, void* d_ws, size_t ws_size,
                              hipStream_t stream) {
    const float* emb0    = (const float*)d_in[0];
    const float* emb1    = (const float*)d_in[1];
    const float* rctx0   = (const float*)d_in[2];
    const float* rctx1   = (const float*)d_in[3];
    const int*   idx0    = (const int*)d_in[4];
    const int*   idx1    = (const int*)d_in[5];
    const float* mean_in = (const float*)d_in[6];
    const float* std_in  = (const float*)d_in[7];
    const float* W1      = (const float*)d_in[8];
    const float* b1      = (const float*)d_in[9];
    const float* Wm      = (const float*)d_in[10];
    const float* bm      = (const float*)d_in[11];
    const float* Ws      = (const float*)d_in[12];
    const float* bs      = (const float*)d_in[13];

    const int B = in_sizes[4];          // 512
    const int N = in_sizes[0] / 16;     // 50000

    u64* chunkTop = (u64*)d_ws;         // [2][B][CNK][20] u64 = 1.31 MB

    knn_scan_kernel<<<dim3(2 * (B / QB) * CNK), NTA, 0, stream>>>(
        emb0, emb1, idx0, idx1, chunkTop, N, B);

    merge_mlp_kernel<<<dim3(B), 128, 0, stream>>>(
        chunkTop, rctx0, rctx1, mean_in, std_in,
        W1, b1, Wm, bm, Ws, bs, (float*)d_out, N, B);
}